// Round 9
// baseline (4829.741 us; speedup 1.0000x reference)
//
#include <hip/hip_runtime.h>
#include <hip/hip_bf16.h>
#include <cmath>

// Problem constants
#define BB    32
#define SS    256
#define AA    6
#define HH    1024
#define OBSF  520
#define GLOBF 30
#define MASKF 52
#define AGFF  73
#define NSEQ  192   // B*A
#define EMBD  512

#define THR_GRU  192
#define LDS_W_BYTES (48*3*64*16)   // 147456 B: 48 kt x 3 gates x 64 lanes x 16B frags

typedef short bf16x8 __attribute__((ext_vector_type(8)));
typedef float f32x4  __attribute__((ext_vector_type(4)));

__device__ __forceinline__ float sigmoidf_(float x){ return 1.f/(1.f + expf(-x)); }
__device__ __forceinline__ short f2bf(float x){
    __hip_bfloat16 h = __float2bfloat16(x);
    return *reinterpret_cast<short*>(&h);
}

// ---------------------------------------------------------------------------
__global__ __launch_bounds__(256) void cvt_bf16(
    const float* __restrict__ in, __hip_bfloat16* __restrict__ out, int n)
{
    for (int i = blockIdx.x*256 + threadIdx.x; i < n; i += gridDim.x*256)
        out[i] = __float2bfloat16(in[i]);
}

// ---------------------------------------------------------------------------
// emb[n][s][d] = relu( sum_f vec[n,s,f] * W_emb[ty_n][f][d] + b_emb[ty_n][d] )
// ---------------------------------------------------------------------------
__global__ __launch_bounds__(256) void emb_kernel(
    const float* __restrict__ inp, const float* __restrict__ W_emb,
    const float* __restrict__ b_emb, __hip_bfloat16* __restrict__ emb)
{
    const int n  = blockIdx.x;          // 0..191
    const int s0 = blockIdx.y * 16;
    const int b  = n / AA, a = n % AA;
    const int tid = threadIdx.x;
    const int ty = (int)inp[(size_t)(b*SS)*OBSF + GLOBF + a*AGFF + 1];

    __shared__ float vecs[16][102];
    for (int idx = tid; idx < 16*102; idx += 256) {
        int ss = idx / 102, f = idx % 102;
        int g  = f + 1;
        int col = (g < AGFF) ? (GLOBF + a*AGFF + g) : (g - AGFF);
        vecs[ss][f] = inp[((size_t)(b*SS + s0 + ss))*OBSF + col];
    }
    __syncthreads();

    float acc0[16], acc1[16];
    #pragma unroll
    for (int ss = 0; ss < 16; ++ss) { acc0[ss] = 0.f; acc1[ss] = 0.f; }

    const float* Wb = W_emb + (size_t)ty*102*EMBD;
    for (int f = 0; f < 102; ++f) {
        float w0 = Wb[f*EMBD + tid];
        float w1 = Wb[f*EMBD + tid + 256];
        #pragma unroll
        for (int ss = 0; ss < 16; ++ss) {
            float v = vecs[ss][f];
            acc0[ss] += v * w0;
            acc1[ss] += v * w1;
        }
    }
    float bb0 = b_emb[ty*EMBD + tid], bb1 = b_emb[ty*EMBD + tid + 256];
    for (int ss = 0; ss < 16; ++ss) {
        __hip_bfloat16* o = emb + ((size_t)n*SS + s0 + ss)*EMBD;
        o[tid]       = __float2bfloat16(fmaxf(acc0[ss] + bb0, 0.f));
        o[tid + 256] = __float2bfloat16(fmaxf(acc1[ss] + bb1, 0.f));
    }
}

// ---------------------------------------------------------------------------
// One GRU step, launched once per s. Grid sync = kernel boundary (HW-managed
// coherence; the ~10us/step software-barrier floor of the persistent variants
// r3-r8 is replaced by graph-replayed dispatch overhead).
// grid 256 = (nt = bx&63) x (mg = bx>>6), 192 thr (3 waves, 1 block/CU).
// wave w owns m-tile mt = mg*3+w: a 16x16 C-tile at rows mt*16.., cols i0...
// - W slice re-staged into LDS each launch (the cost of losing persistence).
// - ALL h A-frags + fp32 h issued BEFORE __syncthreads to overlap staging.
// - acc cols: r, z, n_h, n_x (n-gate split: r multiplies only the h-part).
// - normal cached loads/stores everywhere; no atomics, no fences.
// ---------------------------------------------------------------------------
__global__ __launch_bounds__(THR_GRU, 1) void gru_step_v2(
    const float* __restrict__ h32_in, const short* __restrict__ hbf_in,
    float* __restrict__ h32_out, short* __restrict__ hbf_out,
    const short* __restrict__ emb_bf,
    const short* __restrict__ Whh_bf, const short* __restrict__ Wih_bf,
    const float* __restrict__ b_ih, const float* __restrict__ b_hh, int s)
{
    extern __shared__ short ldsW[];      // [32kt][3g][64lane][8] + [16kt][3g][64lane][8]
    __shared__ short ldsH[3*256];        // per-wave 16x16 bf16 out-tile stage
    const int tid = threadIdx.x, wave = tid >> 6, lane = tid & 63;
    const int nt = blockIdx.x & 63, mg = blockIdx.x >> 6;
    const int i0 = nt*16, mt = mg*3 + wave;
    const int col = lane & 15, rgrp = lane >> 4;
    const int n = i0 + col;

    // ---- stage W slice into LDS as pre-permuted B-frags ----
    for (int idx = tid; idx < 32*3*64; idx += THR_GRU) {
        int l = idx & 63, g = (idx >> 6) % 3, kt = idx / 192;
        const short* src = Whh_bf + ((size_t)(g*HH + i0 + (l & 15)))*HH + kt*32 + (l >> 4)*8;
        *(bf16x8*)(ldsW + (size_t)idx*8) = *(const bf16x8*)src;
    }
    short* ldsW2 = ldsW + 32*3*64*8;
    for (int idx = tid; idx < 16*3*64; idx += THR_GRU) {
        int l = idx & 63, g = (idx >> 6) % 3, kt = idx / 192;
        const short* src = Wih_bf + ((size_t)(g*HH + i0 + (l & 15)))*EMBD + kt*32 + (l >> 4)*8;
        *(bf16x8*)(ldsW2 + (size_t)idx*8) = *(const bf16x8*)src;
    }

    // ---- issue ALL h A-frag loads + fp32 h loads before the sync ----
    const short* Ah = hbf_in + (size_t)(mt*16 + col)*HH + rgrp*8;
    bf16x8 fa[32];
    #pragma unroll
    for (int j = 0; j < 32; ++j) fa[j] = *(const bf16x8*)(Ah + j*32);

    float hprev[4];
    #pragma unroll
    for (int r_ = 0; r_ < 4; ++r_)
        hprev[r_] = h32_in[(size_t)(mt*16 + rgrp*4 + r_)*HH + n];

    __syncthreads();   // LDS W ready

    // ---- x-part: K=512, emb loads in-loop (overlap with MFMA pipeline) ----
    f32x4 ax0 = {0.f,0.f,0.f,0.f}, ax1 = ax0, ax3 = ax0;
    {
        const short* Ae = emb_bf + ((size_t)(mt*16 + col)*SS + s)*EMBD + rgrp*8;
        #pragma unroll 8
        for (int kt = 0; kt < 16; ++kt) {
            bf16x8 a  = *(const bf16x8*)(Ae + kt*32);
            bf16x8 b0 = *(const bf16x8*)(ldsW2 + ((kt*3 + 0)*64 + lane)*8);
            bf16x8 b1 = *(const bf16x8*)(ldsW2 + ((kt*3 + 1)*64 + lane)*8);
            bf16x8 b2 = *(const bf16x8*)(ldsW2 + ((kt*3 + 2)*64 + lane)*8);
            ax0 = __builtin_amdgcn_mfma_f32_16x16x32_bf16(a, b0, ax0, 0,0,0);
            ax1 = __builtin_amdgcn_mfma_f32_16x16x32_bf16(a, b1, ax1, 0,0,0);
            ax3 = __builtin_amdgcn_mfma_f32_16x16x32_bf16(a, b2, ax3, 0,0,0);
        }
    }
    // ---- h-part: K=1024, A-frags already in registers ----
    f32x4 a0 = ax0, a1 = ax1, a2 = {0.f,0.f,0.f,0.f};
    #pragma unroll
    for (int kt = 0; kt < 32; ++kt) {
        bf16x8 b0 = *(const bf16x8*)(ldsW + ((kt*3 + 0)*64 + lane)*8);
        bf16x8 b1 = *(const bf16x8*)(ldsW + ((kt*3 + 1)*64 + lane)*8);
        bf16x8 b2 = *(const bf16x8*)(ldsW + ((kt*3 + 2)*64 + lane)*8);
        a0 = __builtin_amdgcn_mfma_f32_16x16x32_bf16(fa[kt], b0, a0, 0,0,0);
        a1 = __builtin_amdgcn_mfma_f32_16x16x32_bf16(fa[kt], b1, a1, 0,0,0);
        a2 = __builtin_amdgcn_mfma_f32_16x16x32_bf16(fa[kt], b2, a2, 0,0,0);
    }

    // ---- epilogue: gates, fp32 out, bf16 shadow via LDS redistribution ----
    const float bir = b_ih[n], biz = b_ih[HH+n], bin_ = b_ih[2*HH+n];
    const float bhr = b_hh[n], bhz = b_hh[HH+n], bhn  = b_hh[2*HH+n];
    #pragma unroll
    for (int r_ = 0; r_ < 4; ++r_) {
        float r  = sigmoidf_(a0[r_] + bir + bhr);
        float z  = sigmoidf_(a1[r_] + biz + bhz);
        float nn = tanhf(ax3[r_] + bin_ + r*(a2[r_] + bhn));
        float hv = (1.f - z)*nn + z*hprev[r_];
        h32_out[(size_t)(mt*16 + rgrp*4 + r_)*HH + n] = hv;
        ldsH[wave*256 + (rgrp*4 + r_)*16 + col] = f2bf(hv);
    }
    __syncthreads();
    {
        int w2 = tid >> 6, rem = tid & 63, rr = rem >> 2, cg = rem & 3;
        unsigned long long v = *(const unsigned long long*)(ldsH + w2*256 + rr*16 + cg*4);
        *(unsigned long long*)(hbf_out + (size_t)((mg*3 + w2)*16 + rr)*HH + i0 + cg*4) = v;
    }
}

// ---------------------------------------------------------------------------
// Generic row-major SGEMM C[M,N] = A[M,K] @ B[K,N]. 64x64 tiles, 4x4/thread.
// ---------------------------------------------------------------------------
__global__ __launch_bounds__(256) void sgemm_rrr(
    const float* __restrict__ A, const float* __restrict__ B,
    float* __restrict__ C, int M, int N, int K)
{
    const int n0 = blockIdx.x * 64;
    const int m0 = blockIdx.y * 64;
    const int tid = threadIdx.x;
    const int tn = tid & 15, tm = tid >> 4;

    __shared__ float As[16][68];
    __shared__ float Bs[16][68];
    float acc[4][4];
    #pragma unroll
    for (int i = 0; i < 4; ++i)
        #pragma unroll
        for (int j = 0; j < 4; ++j) acc[i][j] = 0.f;

    for (int k0 = 0; k0 < K; k0 += 16) {
        {
            int ml = tid >> 2, k4 = (tid & 3) << 2;
            float4 av = *(const float4*)(A + (size_t)(m0 + ml)*K + k0 + k4);
            As[k4 + 0][ml] = av.x; As[k4 + 1][ml] = av.y;
            As[k4 + 2][ml] = av.z; As[k4 + 3][ml] = av.w;
            int kl = tid >> 4, n4 = (tid & 15) << 2;
            *(float4*)&Bs[kl][n4] = *(const float4*)(B + (size_t)(k0 + kl)*N + n0 + n4);
        }
        __syncthreads();
        #pragma unroll
        for (int kk = 0; kk < 16; ++kk) {
            float4 a4 = *(float4*)&As[kk][tm << 2];
            float4 b4 = *(float4*)&Bs[kk][tn << 2];
            acc[0][0] += a4.x*b4.x; acc[0][1] += a4.x*b4.y; acc[0][2] += a4.x*b4.z; acc[0][3] += a4.x*b4.w;
            acc[1][0] += a4.y*b4.x; acc[1][1] += a4.y*b4.y; acc[1][2] += a4.y*b4.z; acc[1][3] += a4.y*b4.w;
            acc[2][0] += a4.z*b4.x; acc[2][1] += a4.z*b4.y; acc[2][2] += a4.z*b4.z; acc[2][3] += a4.z*b4.w;
            acc[3][0] += a4.w*b4.x; acc[3][1] += a4.w*b4.y; acc[3][2] += a4.w*b4.z; acc[3][3] += a4.w*b4.w;
        }
        __syncthreads();
    }
    #pragma unroll
    for (int qm = 0; qm < 4; ++qm) {
        float4 v = make_float4(acc[qm][0], acc[qm][1], acc[qm][2], acc[qm][3]);
        *(float4*)(C + (size_t)(m0 + tm*4 + qm)*N + n0 + tn*4) = v;
    }
}

// ---------------------------------------------------------------------------
// GAT attention. One block per batch b.
// ---------------------------------------------------------------------------
__global__ __launch_bounds__(256) void gat_att(
    const float* __restrict__ hf, const float* __restrict__ a_s,
    const float* __restrict__ a_d, float* __restrict__ gout)
{
    const int b = blockIdx.x;
    const int tid = threadIdx.x;
    __shared__ float hfs[6][1024];
    __shared__ float srcs[24], dsts[24];
    __shared__ float att[4][36];

    for (int idx = tid; idx < 6*1024; idx += 256)
        hfs[idx >> 10][idx & 1023] = hf[(size_t)b*6144 + idx];
    __syncthreads();

    const int w = tid >> 6, lane = tid & 63;
    for (int p = w; p < 24; p += 4) {
        int h = p / 6, nn = p % 6;
        float as_ = 0.f, ad_ = 0.f;
        for (int c = lane; c < 256; c += 64) {
            float v = hfs[nn][h*256 + c];
            as_ += v * a_s[h*256 + c];
            ad_ += v * a_d[h*256 + c];
        }
        #pragma unroll
        for (int off = 32; off; off >>= 1) {
            as_ += __shfl_down(as_, off);
            ad_ += __shfl_down(ad_, off);
        }
        if (lane == 0) { srcs[p] = as_; dsts[p] = ad_; }
    }
    __syncthreads();

    if (tid < 24) {
        int h = tid / 6, i = tid % 6;
        float e[6], mx = -1e30f;
        #pragma unroll
        for (int j = 0; j < 6; ++j) {
            float x = srcs[h*6 + i] + dsts[h*6 + j];
            e[j] = (x >= 0.f) ? x : 0.2f*x;
            mx = fmaxf(mx, e[j]);
        }
        float sum = 0.f;
        #pragma unroll
        for (int j = 0; j < 6; ++j) { e[j] = expf(e[j] - mx); sum += e[j]; }
        float inv = 1.f / sum;
        #pragma unroll
        for (int j = 0; j < 6; ++j) att[h][i*6 + j] = e[j]*inv;
    }
    __syncthreads();

    for (int idx = tid; idx < 6144; idx += 256) {
        int i = idx >> 10, hd = idx & 1023, h = hd >> 8;
        float v = 0.f;
        #pragma unroll
        for (int j = 0; j < 6; ++j) v += att[h][i*6 + j] * hfs[j][hd];
        gout[(size_t)b*6144 + idx] = (v > 0.f) ? v : (expf(v) - 1.f);
    }
}

// ---------------------------------------------------------------------------
// Head. One block per batch b.
// ---------------------------------------------------------------------------
__global__ __launch_bounds__(256) void head_kernel(
    const float* __restrict__ g1, const float* __restrict__ inp,
    const float* __restrict__ Wa1, const float* __restrict__ ba1,
    const float* __restrict__ Wa2, const float* __restrict__ ba2,
    float* __restrict__ out)
{
    const int b = blockIdx.x;
    const int tid = threadIdx.x;
    const int pt = (int)inp[(size_t)b*SS*OBSF + GLOBF + 1];

    __shared__ float f0s[1024];
    __shared__ float h1s[512];
    __shared__ float lgs[52];

    for (int idx = tid; idx < 1024; idx += 256) f0s[idx] = g1[(size_t)b*6144 + idx];
    __syncthreads();
    {
        float acc0 = 0.f, acc1 = 0.f;
        const float* W = Wa1 + (size_t)pt*1024*512;
        for (int f = 0; f < 1024; ++f) {
            float v = f0s[f];
            acc0 += v * W[f*512 + tid];
            acc1 += v * W[f*512 + tid + 256];
        }
        h1s[tid]       = fmaxf(acc0 + ba1[pt*512 + tid], 0.f);
        h1s[tid + 256] = fmaxf(acc1 + ba1[pt*512 + tid + 256], 0.f);
    }
    __syncthreads();
    if (tid < 52) {
        float acc = 0.f;
        const float* W = Wa2 + (size_t)pt*512*52;
        for (int f = 0; f < 512; ++f) acc += h1s[f] * W[f*52 + tid];
        lgs[tid] = acc + ba2[pt*52 + tid];
    }
    __syncthreads();
    for (int idx = tid; idx < SS*MASKF; idx += 256) {
        int s = idx / MASKF, c = idx % MASKF;
        float mv = inp[((size_t)b*SS + s)*OBSF + (OBSF - MASKF) + c];
        out[(size_t)b*SS*MASKF + idx] = (mv != 0.f) ? lgs[c] : 0.f;
    }
}

// ---------------------------------------------------------------------------
extern "C" void kernel_launch(void* const* d_in, const int* in_sizes, int n_in,
                              void* d_out, int out_size, void* d_ws, size_t ws_size,
                              hipStream_t stream)
{
    const float* inp    = (const float*)d_in[0];
    const float* state0 = (const float*)d_in[1];
    const float* W_emb  = (const float*)d_in[2];
    const float* b_emb  = (const float*)d_in[3];
    const float* W_ih   = (const float*)d_in[4];
    const float* W_hh   = (const float*)d_in[5];
    const float* b_ih   = (const float*)d_in[6];
    const float* b_hh   = (const float*)d_in[7];
    const float* Wg0    = (const float*)d_in[8];
    const float* a0s    = (const float*)d_in[9];
    const float* a0d    = (const float*)d_in[10];
    const float* Wg1    = (const float*)d_in[11];
    const float* a1s    = (const float*)d_in[12];
    const float* a1d    = (const float*)d_in[13];
    const float* Wa1    = (const float*)d_in[14];
    const float* ba1    = (const float*)d_in[15];
    const float* Wa2    = (const float*)d_in[16];
    const float* ba2    = (const float*)d_in[17];
    float* out = (float*)d_out;

    // workspace layout (bytes)
    char* p = (char*)d_ws;
    __hip_bfloat16* emb_bf = (__hip_bfloat16*)p;  p += (size_t)NSEQ*SS*EMBD*2;   // 50.3 MB
    __hip_bfloat16* Whh_bf = (__hip_bfloat16*)p;  p += (size_t)3*HH*HH*2;
    __hip_bfloat16* Wih_bf = (__hip_bfloat16*)p;  p += (size_t)3*HH*EMBD*2;
    float* hb0 = (float*)p;                       p += (size_t)NSEQ*HH*4;
    float* hb1 = (float*)p;                       p += (size_t)NSEQ*HH*4;
    short* hbf0 = (short*)p;                      p += (size_t)NSEQ*HH*2;
    short* hbf1 = (short*)p;                      p += (size_t)NSEQ*HH*2;
    float* hf = (float*)p;                        p += (size_t)NSEQ*HH*4;
    float* g0 = (float*)p;                        p += (size_t)NSEQ*HH*4;
    float* g1 = (float*)p;                        p += (size_t)NSEQ*HH*4;
    if (ws_size < (size_t)(p - (char*)d_ws)) return;

    // 0) W -> bf16
    cvt_bf16<<<512, 256, 0, stream>>>(W_hh, Whh_bf, 3*HH*HH);
    cvt_bf16<<<512, 256, 0, stream>>>(W_ih, Wih_bf, 3*HH*EMBD);

    // 1) embedding (bf16 out)
    emb_kernel<<<dim3(NSEQ, 16), 256, 0, stream>>>(inp, W_emb, b_emb, emb_bf);

    // 2) GRU: 256 per-step launches (HW grid sync at kernel boundary)
    static int attr_set = 0;
    if (!attr_set) {
        hipFuncSetAttribute((const void*)gru_step_v2,
                            hipFuncAttributeMaxDynamicSharedMemorySize, LDS_W_BYTES);
        attr_set = 1;
    }
    cvt_bf16<<<192, 256, 0, stream>>>(state0, (__hip_bfloat16*)hbf0, NSEQ*HH);
    hipMemcpyAsync(hb0, state0, (size_t)NSEQ*HH*4, hipMemcpyDeviceToDevice, stream);

    const short* emb_bf_s = (const short*)emb_bf;
    const short* Whh_bf_s = (const short*)Whh_bf;
    const short* Wih_bf_s = (const short*)Wih_bf;
    float* hf32[2] = {hb0, hb1};
    short* hbf[2]  = {hbf0, hbf1};
    for (int s = 0; s < SS; ++s) {
        gru_step_v2<<<256, THR_GRU, LDS_W_BYTES, stream>>>(
            hf32[s & 1], hbf[s & 1], hf32[(s + 1) & 1], hbf[(s + 1) & 1],
            emb_bf_s, Whh_bf_s, Wih_bf_s, b_ih, b_hh, s);
    }
    const float* hT = hb0;   // 256 steps -> ends in buffer 0

    // hT output region
    hipMemcpyAsync(out + (size_t)BB*SS*MASKF, hb0, (size_t)NSEQ*HH*4,
                   hipMemcpyDeviceToDevice, stream);

    // 3) GAT layer 0
    sgemm_rrr<<<dim3(16, 3), 256, 0, stream>>>(hT, Wg0, hf, NSEQ, HH, HH);
    gat_att<<<BB, 256, 0, stream>>>(hf, a0s, a0d, g0);
    // 4) GAT layer 1
    sgemm_rrr<<<dim3(16, 3), 256, 0, stream>>>(g0, Wg1, hf, NSEQ, HH, HH);
    gat_att<<<BB, 256, 0, stream>>>(hf, a1s, a1d, g1);

    // 5) head + masked broadcast
    head_kernel<<<BB, 256, 0, stream>>>(g1, inp, Wa1, ba1, Wa2, ba2, out);
}

// Round 10
// 3201.605 us; speedup vs baseline: 1.5085x; 1.5085x over previous
//
#include <hip/hip_runtime.h>
#include <hip/hip_bf16.h>
#include <cmath>

// Problem constants
#define BB    32
#define SS    256
#define AA    6
#define HH    1024
#define OBSF  520
#define GLOBF 30
#define MASKF 52
#define AGFF  73
#define NSEQ  192   // B*A
#define EMBD  512

#define GRID_GRU 256
#define THR_GRU  192
#define LDS_W_BYTES (48*3*64*16)   // 147456 B: 48 kt x 3 gates x 64 lanes x 16B frags

typedef short bf16x8 __attribute__((ext_vector_type(8)));
typedef float f32x4  __attribute__((ext_vector_type(4)));

__device__ __forceinline__ float sigmoidf_(float x){ return 1.f/(1.f + expf(-x)); }
__device__ __forceinline__ short f2bf(float x){
    __hip_bfloat16 h = __float2bfloat16(x);
    return *reinterpret_cast<short*>(&h);
}

// 16B h-fragment via two 8B agent-relaxed atomic loads: lowers to
// global_load_dwordx2 with L1/L2 bypass -> always reads the LLC coherence
// point. No acquire fence / buffer_inv needed anywhere.
__device__ __forceinline__ bf16x8 load_bypass16(const short* p){
    union { unsigned long long u[2]; bf16x8 v; } x;
    x.u[0] = __hip_atomic_load((const unsigned long long*)p,     __ATOMIC_RELAXED, __HIP_MEMORY_SCOPE_AGENT);
    x.u[1] = __hip_atomic_load((const unsigned long long*)(p+4), __ATOMIC_RELAXED, __HIP_MEMORY_SCOPE_AGENT);
    return x.v;
}

// ---------------------------------------------------------------------------
__global__ __launch_bounds__(256) void cvt_bf16(
    const float* __restrict__ in, __hip_bfloat16* __restrict__ out, int n)
{
    for (int i = blockIdx.x*256 + threadIdx.x; i < n; i += gridDim.x*256)
        out[i] = __float2bfloat16(in[i]);
}

// ---------------------------------------------------------------------------
// emb[n][s][d] = relu( sum_f vec[n,s,f] * W_emb[ty_n][f][d] + b_emb[ty_n][d] )
// ---------------------------------------------------------------------------
__global__ __launch_bounds__(256) void emb_kernel(
    const float* __restrict__ inp, const float* __restrict__ W_emb,
    const float* __restrict__ b_emb, __hip_bfloat16* __restrict__ emb)
{
    const int n  = blockIdx.x;          // 0..191
    const int s0 = blockIdx.y * 16;
    const int b  = n / AA, a = n % AA;
    const int tid = threadIdx.x;
    const int ty = (int)inp[(size_t)(b*SS)*OBSF + GLOBF + a*AGFF + 1];

    __shared__ float vecs[16][102];
    for (int idx = tid; idx < 16*102; idx += 256) {
        int ss = idx / 102, f = idx % 102;
        int g  = f + 1;
        int col = (g < AGFF) ? (GLOBF + a*AGFF + g) : (g - AGFF);
        vecs[ss][f] = inp[((size_t)(b*SS + s0 + ss))*OBSF + col];
    }
    __syncthreads();

    float acc0[16], acc1[16];
    #pragma unroll
    for (int ss = 0; ss < 16; ++ss) { acc0[ss] = 0.f; acc1[ss] = 0.f; }

    const float* Wb = W_emb + (size_t)ty*102*EMBD;
    for (int f = 0; f < 102; ++f) {
        float w0 = Wb[f*EMBD + tid];
        float w1 = Wb[f*EMBD + tid + 256];
        #pragma unroll
        for (int ss = 0; ss < 16; ++ss) {
            float v = vecs[ss][f];
            acc0[ss] += v * w0;
            acc1[ss] += v * w1;
        }
    }
    float bb0 = b_emb[ty*EMBD + tid], bb1 = b_emb[ty*EMBD + tid + 256];
    for (int ss = 0; ss < 16; ++ss) {
        __hip_bfloat16* o = emb + ((size_t)n*SS + s0 + ss)*EMBD;
        o[tid]       = __float2bfloat16(fmaxf(acc0[ss] + bb0, 0.f));
        o[tid + 256] = __float2bfloat16(fmaxf(acc1[ss] + bb1, 0.f));
    }
}

// ---------------------------------------------------------------------------
// Persistent cooperative GRU, v5 = r8 structure with the arrival RMW
// replaced by an RMW-free flag barrier:
//  - arrival: block (nt,mg) STORES flags[nt] = s+2 (relaxed bypass store;
//    64 parallel stores instead of 64 serialized fetch_adds on one address)
//  - detection: wave 0 reads all 64 flags with ONE coalesced 64-lane bypass
//    load and checks __ballot(flag >= target) == all-ones (monotonic step
//    counts -> no reset race).
// Ordering skeleton identical to r8 (verified): vmcnt drain + __syncthreads
// before the flag store; x-part of s+1 between store and poll.
// grid 256 x 192thr (1 block/CU). block = (nt = bx&63, mg = bx>>6).
// wave w owns m-tile mt = mg*3+w. All 32 h A-frag bypass loads up-front.
// ---------------------------------------------------------------------------
__global__ __launch_bounds__(THR_GRU, 1) void gru_persistent(
    const float* __restrict__ state0,
    const short* __restrict__ emb_bf,
    const short* __restrict__ Whh_bf, const short* __restrict__ Wih_bf,
    const float* __restrict__ b_ih, const float* __restrict__ b_hh,
    short* __restrict__ hbf0, short* __restrict__ hbf1,
    float* __restrict__ hT_out, unsigned* __restrict__ bar)
{
    extern __shared__ short ldsW[];      // [32kt][3g][64lane][8] + [16kt][3g][64lane][8]
    __shared__ short ldsH[3*256];        // per-wave 16x16 bf16 out-tile stage
    const int tid = threadIdx.x, wave = tid >> 6, lane = tid & 63;
    const int nt = blockIdx.x & 63, mg = blockIdx.x >> 6;
    const int i0 = nt*16, mt = mg*3 + wave;
    const int col = lane & 15, rgrp = lane >> 4;
    const int n = i0 + col;
    unsigned* flags = bar + mg*64;       // 64 per-block step flags for this mg

    // ---- stage W into LDS as pre-permuted B-frags (16B cached loads) ----
    for (int idx = tid; idx < 32*3*64; idx += THR_GRU) {
        int l = idx & 63, g = (idx >> 6) % 3, kt = idx / 192;
        const short* src = Whh_bf + ((size_t)(g*HH + i0 + (l & 15)))*HH + kt*32 + (l >> 4)*8;
        *(bf16x8*)(ldsW + (size_t)idx*8) = *(const bf16x8*)src;
    }
    short* ldsW2 = ldsW + 32*3*64*8;
    for (int idx = tid; idx < 16*3*64; idx += THR_GRU) {
        int l = idx & 63, g = (idx >> 6) % 3, kt = idx / 192;
        const short* src = Wih_bf + ((size_t)(g*HH + i0 + (l & 15)))*EMBD + kt*32 + (l >> 4)*8;
        *(bf16x8*)(ldsW2 + (size_t)idx*8) = *(const bf16x8*)src;
    }

    // ---- init h regs + stage bf16 shadow ----
    float hreg[4];
    #pragma unroll
    for (int r_ = 0; r_ < 4; ++r_) {
        hreg[r_] = state0[(size_t)(mt*16 + rgrp*4 + r_)*HH + n];
        ldsH[wave*256 + (rgrp*4 + r_)*16 + col] = f2bf(hreg[r_]);
    }
    __syncthreads();   // W staging + ldsH init complete
    {
        int w2 = tid >> 6, rem = tid & 63, rr = rem >> 2, cg = rem & 3;
        unsigned long long v = *(const unsigned long long*)(ldsH + w2*256 + rr*16 + cg*4);
        __hip_atomic_store((unsigned long long*)(hbf0 + (size_t)((mg*3 + w2)*16 + rr)*HH + i0 + cg*4),
                           v, __ATOMIC_RELAXED, __HIP_MEMORY_SCOPE_AGENT);
    }
    asm volatile("s_waitcnt vmcnt(0)" ::: "memory");
    __syncthreads();
    if (tid == 0)
        __hip_atomic_store(&flags[nt], 1u, __ATOMIC_RELAXED, __HIP_MEMORY_SCOPE_AGENT);

    const float bir = b_ih[n], biz = b_ih[HH+n], bin_ = b_ih[2*HH+n];
    const float bhr = b_hh[n], bhz = b_hh[HH+n], bhn  = b_hh[2*HH+n];

    const size_t lane_h_off = (size_t)(mt*16 + col)*HH + rgrp*8;
    const size_t lane_e_off = (size_t)(mt*16 + col)*SS*EMBD + rgrp*8;

    // ---- x-part for s = 0 (hidden behind other blocks' init) ----
    f32x4 ax0 = {0.f,0.f,0.f,0.f}, ax1 = ax0, ax3 = ax0;
    {
        const short* Ae = emb_bf + lane_e_off;
        #pragma unroll 8
        for (int kt = 0; kt < 16; ++kt) {
            bf16x8 a  = *(const bf16x8*)(Ae + kt*32);
            bf16x8 b0 = *(const bf16x8*)(ldsW2 + ((kt*3 + 0)*64 + lane)*8);
            bf16x8 b1 = *(const bf16x8*)(ldsW2 + ((kt*3 + 1)*64 + lane)*8);
            bf16x8 b2 = *(const bf16x8*)(ldsW2 + ((kt*3 + 2)*64 + lane)*8);
            ax0 = __builtin_amdgcn_mfma_f32_16x16x32_bf16(a, b0, ax0, 0,0,0);
            ax1 = __builtin_amdgcn_mfma_f32_16x16x32_bf16(a, b1, ax1, 0,0,0);
            ax3 = __builtin_amdgcn_mfma_f32_16x16x32_bf16(a, b2, ax3, 0,0,0);
        }
    }
    if (wave == 0) {
        for (;;) {
            unsigned f = __hip_atomic_load(&flags[lane], __ATOMIC_RELAXED, __HIP_MEMORY_SCOPE_AGENT);
            if (__ballot(f >= 1u) == ~0ull) break;
            __builtin_amdgcn_s_sleep(1);
        }
    }
    __syncthreads();

    for (int s = 0; s < SS; ++s) {
        const short* cur = (s & 1) ? hbf1 : hbf0;
        short*       nxt = (s & 1) ? hbf0 : hbf1;

        // ---- h-part: issue ALL 32 A-frag bypass loads up-front ----
        const short* Ah = cur + lane_h_off;
        bf16x8 fa[32];
        #pragma unroll
        for (int j = 0; j < 32; ++j) fa[j] = load_bypass16(Ah + j*32);

        f32x4 a0 = ax0, a1 = ax1, a2 = {0.f,0.f,0.f,0.f};
        #pragma unroll
        for (int kt = 0; kt < 32; ++kt) {
            bf16x8 b0 = *(const bf16x8*)(ldsW + ((kt*3 + 0)*64 + lane)*8);
            bf16x8 b1 = *(const bf16x8*)(ldsW + ((kt*3 + 1)*64 + lane)*8);
            bf16x8 b2 = *(const bf16x8*)(ldsW + ((kt*3 + 2)*64 + lane)*8);
            a0 = __builtin_amdgcn_mfma_f32_16x16x32_bf16(fa[kt], b0, a0, 0,0,0);
            a1 = __builtin_amdgcn_mfma_f32_16x16x32_bf16(fa[kt], b1, a1, 0,0,0);
            a2 = __builtin_amdgcn_mfma_f32_16x16x32_bf16(fa[kt], b2, a2, 0,0,0);
        }

        // ---- epilogue: gates (x-part in ax*), update regs, stage tile ----
        #pragma unroll
        for (int r_ = 0; r_ < 4; ++r_) {
            float r  = sigmoidf_(a0[r_] + bir + bhr);
            float z  = sigmoidf_(a1[r_] + biz + bhz);
            float nn = tanhf(ax3[r_] + bin_ + r*(a2[r_] + bhn));
            float hv = (1.f - z)*nn + z*hreg[r_];
            hreg[r_] = hv;
            ldsH[wave*256 + (rgrp*4 + r_)*16 + col] = f2bf(hv);
        }

        if (s < SS-1) {
            __syncthreads();
            {
                int w2 = tid >> 6, rem = tid & 63, rr = rem >> 2, cg = rem & 3;
                unsigned long long v = *(const unsigned long long*)(ldsH + w2*256 + rr*16 + cg*4);
                __hip_atomic_store((unsigned long long*)(nxt + (size_t)((mg*3 + w2)*16 + rr)*HH + i0 + cg*4),
                                   v, __ATOMIC_RELAXED, __HIP_MEMORY_SCOPE_AGENT);
            }
            asm volatile("s_waitcnt vmcnt(0)" ::: "memory");
            __syncthreads();
            if (tid == 0)
                __hip_atomic_store(&flags[nt], (unsigned)(s + 2), __ATOMIC_RELAXED, __HIP_MEMORY_SCOPE_AGENT);

            // ---- x-part for s+1: hidden inside the barrier wait ----
            ax0 = (f32x4){0.f,0.f,0.f,0.f}; ax1 = ax0; ax3 = ax0;
            const short* Ae = emb_bf + lane_e_off + (size_t)(s+1)*EMBD;
            #pragma unroll 8
            for (int kt = 0; kt < 16; ++kt) {
                bf16x8 a  = *(const bf16x8*)(Ae + kt*32);
                bf16x8 b0 = *(const bf16x8*)(ldsW2 + ((kt*3 + 0)*64 + lane)*8);
                bf16x8 b1 = *(const bf16x8*)(ldsW2 + ((kt*3 + 1)*64 + lane)*8);
                bf16x8 b2 = *(const bf16x8*)(ldsW2 + ((kt*3 + 2)*64 + lane)*8);
                ax0 = __builtin_amdgcn_mfma_f32_16x16x32_bf16(a, b0, ax0, 0,0,0);
                ax1 = __builtin_amdgcn_mfma_f32_16x16x32_bf16(a, b1, ax1, 0,0,0);
                ax3 = __builtin_amdgcn_mfma_f32_16x16x32_bf16(a, b2, ax3, 0,0,0);
            }
            {
                unsigned target = (unsigned)(s + 2);
                if (wave == 0) {
                    for (;;) {
                        unsigned f = __hip_atomic_load(&flags[lane], __ATOMIC_RELAXED, __HIP_MEMORY_SCOPE_AGENT);
                        if (__ballot(f >= target) == ~0ull) break;
                        __builtin_amdgcn_s_sleep(1);
                    }
                }
            }
            __syncthreads();
        }
    }

    #pragma unroll
    for (int r_ = 0; r_ < 4; ++r_)
        hT_out[(size_t)(mt*16 + rgrp*4 + r_)*HH + n] = hreg[r_];
}

// ---------------------------------------------------------------------------
// Fallback per-step GRU kernel (round-2 verified path).
// ---------------------------------------------------------------------------
__global__ __launch_bounds__(256) void gru_step_mfma(
    const float* __restrict__ h_in, const __hip_bfloat16* __restrict__ h_in_bf,
    float* __restrict__ h_out, __hip_bfloat16* __restrict__ h_out_bf,
    const __hip_bfloat16* __restrict__ emb_bf,
    const __hip_bfloat16* __restrict__ Whh_bf, const __hip_bfloat16* __restrict__ Wih_bf,
    const float* __restrict__ b_ih, const float* __restrict__ b_hh, int s)
{
    const int i0   = blockIdx.x * 16;
    const int tid  = threadIdx.x;
    const int wave = tid >> 6, lane = tid & 63;
    const int col  = lane & 15, rgrp = lane >> 4;
    const int n    = i0 + col;
    const int kofs = rgrp * 8;

    f32x4 acc[3][4];
    #pragma unroll
    for (int mi = 0; mi < 3; ++mi)
        #pragma unroll
        for (int g = 0; g < 4; ++g) acc[mi][g] = (f32x4){0.f,0.f,0.f,0.f};

    {
        const short* Ab = (const short*)h_in_bf;
        const short* B0 = (const short*)Whh_bf + ((size_t)(      n))*HH + kofs;
        const short* B1 = (const short*)Whh_bf + ((size_t)(HH  + n))*HH + kofs;
        const short* B2 = (const short*)Whh_bf + ((size_t)(2*HH+ n))*HH + kofs;
        #pragma unroll 2
        for (int kt = 0; kt < 32; ++kt) {
            const int kk = kt * 32;
            bf16x8 b0 = *(const bf16x8*)(B0 + kk);
            bf16x8 b1 = *(const bf16x8*)(B1 + kk);
            bf16x8 b2 = *(const bf16x8*)(B2 + kk);
            #pragma unroll
            for (int mi = 0; mi < 3; ++mi) {
                const int m = (wave*3 + mi)*16 + col;
                bf16x8 a = *(const bf16x8*)(Ab + (size_t)m*HH + kk + kofs);
                acc[mi][0] = __builtin_amdgcn_mfma_f32_16x16x32_bf16(a, b0, acc[mi][0], 0,0,0);
                acc[mi][1] = __builtin_amdgcn_mfma_f32_16x16x32_bf16(a, b1, acc[mi][1], 0,0,0);
                acc[mi][2] = __builtin_amdgcn_mfma_f32_16x16x32_bf16(a, b2, acc[mi][2], 0,0,0);
            }
        }
    }
    {
        const short* Ab = (const short*)emb_bf;
        const short* B0 = (const short*)Wih_bf + ((size_t)(      n))*EMBD + kofs;
        const short* B1 = (const short*)Wih_bf + ((size_t)(HH  + n))*EMBD + kofs;
        const short* B2 = (const short*)Wih_bf + ((size_t)(2*HH+ n))*EMBD + kofs;
        #pragma unroll 2
        for (int kt = 0; kt < 16; ++kt) {
            const int kk = kt * 32;
            bf16x8 b0 = *(const bf16x8*)(B0 + kk);
            bf16x8 b1 = *(const bf16x8*)(B1 + kk);
            bf16x8 b2 = *(const bf16x8*)(B2 + kk);
            #pragma unroll
            for (int mi = 0; mi < 3; ++mi) {
                const int m = (wave*3 + mi)*16 + col;
                bf16x8 a = *(const bf16x8*)(Ab + ((size_t)m*SS + s)*EMBD + kk + kofs);
                acc[mi][0] = __builtin_amdgcn_mfma_f32_16x16x32_bf16(a, b0, acc[mi][0], 0,0,0);
                acc[mi][1] = __builtin_amdgcn_mfma_f32_16x16x32_bf16(a, b1, acc[mi][1], 0,0,0);
                acc[mi][3] = __builtin_amdgcn_mfma_f32_16x16x32_bf16(a, b2, acc[mi][3], 0,0,0);
            }
        }
    }
    const float bir = b_ih[n], biz = b_ih[HH + n], bin_ = b_ih[2*HH + n];
    const float bhr = b_hh[n], bhz = b_hh[HH + n], bhn  = b_hh[2*HH + n];
    #pragma unroll
    for (int mi = 0; mi < 3; ++mi) {
        #pragma unroll
        for (int r_ = 0; r_ < 4; ++r_) {
            const int m = (wave*3 + mi)*16 + rgrp*4 + r_;
            float r  = sigmoidf_(acc[mi][0][r_] + bir + bhr);
            float z  = sigmoidf_(acc[mi][1][r_] + biz + bhz);
            float nn = tanhf(acc[mi][3][r_] + bin_ + r*(acc[mi][2][r_] + bhn));
            const size_t idx = (size_t)m*HH + n;
            float hv = (1.f - z)*nn + z*h_in[idx];
            h_out[idx]    = hv;
            h_out_bf[idx] = __float2bfloat16(hv);
        }
    }
}

// ---------------------------------------------------------------------------
// Generic row-major SGEMM C[M,N] = A[M,K] @ B[K,N]. 64x64 tiles, 4x4/thread.
// ---------------------------------------------------------------------------
__global__ __launch_bounds__(256) void sgemm_rrr(
    const float* __restrict__ A, const float* __restrict__ B,
    float* __restrict__ C, int M, int N, int K)
{
    const int n0 = blockIdx.x * 64;
    const int m0 = blockIdx.y * 64;
    const int tid = threadIdx.x;
    const int tn = tid & 15, tm = tid >> 4;

    __shared__ float As[16][68];
    __shared__ float Bs[16][68];
    float acc[4][4];
    #pragma unroll
    for (int i = 0; i < 4; ++i)
        #pragma unroll
        for (int j = 0; j < 4; ++j) acc[i][j] = 0.f;

    for (int k0 = 0; k0 < K; k0 += 16) {
        {
            int ml = tid >> 2, k4 = (tid & 3) << 2;
            float4 av = *(const float4*)(A + (size_t)(m0 + ml)*K + k0 + k4);
            As[k4 + 0][ml] = av.x; As[k4 + 1][ml] = av.y;
            As[k4 + 2][ml] = av.z; As[k4 + 3][ml] = av.w;
            int kl = tid >> 4, n4 = (tid & 15) << 2;
            *(float4*)&Bs[kl][n4] = *(const float4*)(B + (size_t)(k0 + kl)*N + n0 + n4);
        }
        __syncthreads();
        #pragma unroll
        for (int kk = 0; kk < 16; ++kk) {
            float4 a4 = *(float4*)&As[kk][tm << 2];
            float4 b4 = *(float4*)&Bs[kk][tn << 2];
            acc[0][0] += a4.x*b4.x; acc[0][1] += a4.x*b4.y; acc[0][2] += a4.x*b4.z; acc[0][3] += a4.x*b4.w;
            acc[1][0] += a4.y*b4.x; acc[1][1] += a4.y*b4.y; acc[1][2] += a4.y*b4.z; acc[1][3] += a4.y*b4.w;
            acc[2][0] += a4.z*b4.x; acc[2][1] += a4.z*b4.y; acc[2][2] += a4.z*b4.z; acc[2][3] += a4.z*b4.w;
            acc[3][0] += a4.w*b4.x; acc[3][1] += a4.w*b4.y; acc[3][2] += a4.w*b4.z; acc[3][3] += a4.w*b4.w;
        }
        __syncthreads();
    }
    #pragma unroll
    for (int qm = 0; qm < 4; ++qm) {
        float4 v = make_float4(acc[qm][0], acc[qm][1], acc[qm][2], acc[qm][3]);
        *(float4*)(C + (size_t)(m0 + tm*4 + qm)*N + n0 + tn*4) = v;
    }
}

// ---------------------------------------------------------------------------
// GAT attention. One block per batch b.
// ---------------------------------------------------------------------------
__global__ __launch_bounds__(256) void gat_att(
    const float* __restrict__ hf, const float* __restrict__ a_s,
    const float* __restrict__ a_d, float* __restrict__ gout)
{
    const int b = blockIdx.x;
    const int tid = threadIdx.x;
    __shared__ float hfs[6][1024];
    __shared__ float srcs[24], dsts[24];
    __shared__ float att[4][36];

    for (int idx = tid; idx < 6*1024; idx += 256)
        hfs[idx >> 10][idx & 1023] = hf[(size_t)b*6144 + idx];
    __syncthreads();

    const int w = tid >> 6, lane = tid & 63;
    for (int p = w; p < 24; p += 4) {
        int h = p / 6, nn = p % 6;
        float as_ = 0.f, ad_ = 0.f;
        for (int c = lane; c < 256; c += 64) {
            float v = hfs[nn][h*256 + c];
            as_ += v * a_s[h*256 + c];
            ad_ += v * a_d[h*256 + c];
        }
        #pragma unroll
        for (int off = 32; off; off >>= 1) {
            as_ += __shfl_down(as_, off);
            ad_ += __shfl_down(ad_, off);
        }
        if (lane == 0) { srcs[p] = as_; dsts[p] = ad_; }
    }
    __syncthreads();

    if (tid < 24) {
        int h = tid / 6, i = tid % 6;
        float e[6], mx = -1e30f;
        #pragma unroll
        for (int j = 0; j < 6; ++j) {
            float x = srcs[h*6 + i] + dsts[h*6 + j];
            e[j] = (x >= 0.f) ? x : 0.2f*x;
            mx = fmaxf(mx, e[j]);
        }
        float sum = 0.f;
        #pragma unroll
        for (int j = 0; j < 6; ++j) { e[j] = expf(e[j] - mx); sum += e[j]; }
        float inv = 1.f / sum;
        #pragma unroll
        for (int j = 0; j < 6; ++j) att[h][i*6 + j] = e[j]*inv;
    }
    __syncthreads();

    for (int idx = tid; idx < 6144; idx += 256) {
        int i = idx >> 10, hd = idx & 1023, h = hd >> 8;
        float v = 0.f;
        #pragma unroll
        for (int j = 0; j < 6; ++j) v += att[h][i*6 + j] * hfs[j][hd];
        gout[(size_t)b*6144 + idx] = (v > 0.f) ? v : (expf(v) - 1.f);
    }
}

// ---------------------------------------------------------------------------
// Head. One block per batch b.
// ---------------------------------------------------------------------------
__global__ __launch_bounds__(256) void head_kernel(
    const float* __restrict__ g1, const float* __restrict__ inp,
    const float* __restrict__ Wa1, const float* __restrict__ ba1,
    const float* __restrict__ Wa2, const float* __restrict__ ba2,
    float* __restrict__ out)
{
    const int b = blockIdx.x;
    const int tid = threadIdx.x;
    const int pt = (int)inp[(size_t)b*SS*OBSF + GLOBF + 1];

    __shared__ float f0s[1024];
    __shared__ float h1s[512];
    __shared__ float lgs[52];

    for (int idx = tid; idx < 1024; idx += 256) f0s[idx] = g1[(size_t)b*6144 + idx];
    __syncthreads();
    {
        float acc0 = 0.f, acc1 = 0.f;
        const float* W = Wa1 + (size_t)pt*1024*512;
        for (int f = 0; f < 1024; ++f) {
            float v = f0s[f];
            acc0 += v * W[f*512 + tid];
            acc1 += v * W[f*512 + tid + 256];
        }
        h1s[tid]       = fmaxf(acc0 + ba1[pt*512 + tid], 0.f);
        h1s[tid + 256] = fmaxf(acc1 + ba1[pt*512 + tid + 256], 0.f);
    }
    __syncthreads();
    if (tid < 52) {
        float acc = 0.f;
        const float* W = Wa2 + (size_t)pt*512*52;
        for (int f = 0; f < 512; ++f) acc += h1s[f] * W[f*52 + tid];
        lgs[tid] = acc + ba2[pt*52 + tid];
    }
    __syncthreads();
    for (int idx = tid; idx < SS*MASKF; idx += 256) {
        int s = idx / MASKF, c = idx % MASKF;
        float mv = inp[((size_t)b*SS + s)*OBSF + (OBSF - MASKF) + c];
        out[(size_t)b*SS*MASKF + idx] = (mv != 0.f) ? lgs[c] : 0.f;
    }
}

// ---------------------------------------------------------------------------
extern "C" void kernel_launch(void* const* d_in, const int* in_sizes, int n_in,
                              void* d_out, int out_size, void* d_ws, size_t ws_size,
                              hipStream_t stream)
{
    const float* inp    = (const float*)d_in[0];
    const float* state0 = (const float*)d_in[1];
    const float* W_emb  = (const float*)d_in[2];
    const float* b_emb  = (const float*)d_in[3];
    const float* W_ih   = (const float*)d_in[4];
    const float* W_hh   = (const float*)d_in[5];
    const float* b_ih   = (const float*)d_in[6];
    const float* b_hh   = (const float*)d_in[7];
    const float* Wg0    = (const float*)d_in[8];
    const float* a0s    = (const float*)d_in[9];
    const float* a0d    = (const float*)d_in[10];
    const float* Wg1    = (const float*)d_in[11];
    const float* a1s    = (const float*)d_in[12];
    const float* a1d    = (const float*)d_in[13];
    const float* Wa1    = (const float*)d_in[14];
    const float* ba1    = (const float*)d_in[15];
    const float* Wa2    = (const float*)d_in[16];
    const float* ba2    = (const float*)d_in[17];
    float* out = (float*)d_out;

    // workspace layout (bytes)
    char* p = (char*)d_ws;
    __hip_bfloat16* emb_bf = (__hip_bfloat16*)p;  p += (size_t)NSEQ*SS*EMBD*2;   // 50.3 MB
    __hip_bfloat16* Whh_bf = (__hip_bfloat16*)p;  p += (size_t)3*HH*HH*2;
    __hip_bfloat16* Wih_bf = (__hip_bfloat16*)p;  p += (size_t)3*HH*EMBD*2;
    float* hb0 = (float*)p;                       p += (size_t)NSEQ*HH*4;        // fallback
    float* hb1 = (float*)p;                       p += (size_t)NSEQ*HH*4;        // fallback
    short* hbf0 = (short*)p;                      p += (size_t)NSEQ*HH*2;
    short* hbf1 = (short*)p;                      p += (size_t)NSEQ*HH*2;
    float* hf = (float*)p;                        p += (size_t)NSEQ*HH*4;
    float* g0 = (float*)p;                        p += (size_t)NSEQ*HH*4;
    float* g1 = (float*)p;                        p += (size_t)NSEQ*HH*4;
    unsigned* bar = (unsigned*)p;                 p += 4096;   // 4 mg x 64 flags
    if (ws_size < (size_t)(p - (char*)d_ws)) return;

    // 0) W -> bf16 (used by both paths)
    cvt_bf16<<<512, 256, 0, stream>>>(W_hh, Whh_bf, 3*HH*HH);
    cvt_bf16<<<512, 256, 0, stream>>>(W_ih, Wih_bf, 3*HH*EMBD);

    // 1) embedding (bf16 out)
    emb_kernel<<<dim3(NSEQ, 16), 256, 0, stream>>>(inp, W_emb, b_emb, emb_bf);

    // 2) GRU: persistent cooperative kernel (fallback: 256-launch loop)
    hipMemsetAsync(bar, 0, 4096, stream);
    float* hT_out = out + (size_t)BB*SS*MASKF;

    static int attr_set = 0;
    if (!attr_set) {
        hipFuncSetAttribute((const void*)gru_persistent,
                            hipFuncAttributeMaxDynamicSharedMemorySize, LDS_W_BYTES);
        attr_set = 1;
    }
    const short* emb_bf_s = (const short*)emb_bf;
    const short* Whh_bf_s = (const short*)Whh_bf;
    const short* Wih_bf_s = (const short*)Wih_bf;
    void* args[] = { (void*)&state0, (void*)&emb_bf_s, (void*)&Whh_bf_s, (void*)&Wih_bf_s,
                     (void*)&b_ih, (void*)&b_hh, (void*)&hbf0, (void*)&hbf1,
                     (void*)&hT_out, (void*)&bar };
    hipError_t e = hipLaunchCooperativeKernel((const void*)gru_persistent,
                                              dim3(GRID_GRU), dim3(THR_GRU),
                                              args, LDS_W_BYTES, stream);
    const float* hT;
    if (e == hipSuccess) {
        hT = hT_out;
    } else {
        // fallback: round-2 verified path
        cvt_bf16<<<192, 256, 0, stream>>>(state0, (__hip_bfloat16*)hbf0, NSEQ*HH);
        hipMemcpyAsync(hb0, state0, (size_t)NSEQ*HH*4, hipMemcpyDeviceToDevice, stream);
        float* hf32[2] = {hb0, hb1};
        short* hbf[2] = {hbf0, hbf1};
        for (int s = 0; s < SS; ++s) {
            gru_step_mfma<<<64, 256, 0, stream>>>(
                hf32[s & 1], (const __hip_bfloat16*)hbf[s & 1],
                hf32[(s + 1) & 1], (__hip_bfloat16*)hbf[(s + 1) & 1],
                (const __hip_bfloat16*)emb_bf, Whh_bf, Wih_bf, b_ih, b_hh, s);
        }
        hT = hb0;
        hipMemcpyAsync(hT_out, hb0, (size_t)NSEQ*HH*4, hipMemcpyDeviceToDevice, stream);
    }

    // 3) GAT layer 0
    sgemm_rrr<<<dim3(16, 3), 256, 0, stream>>>(hT, Wg0, hf, NSEQ, HH, HH);
    gat_att<<<BB, 256, 0, stream>>>(hf, a0s, a0d, g0);
    // 4) GAT layer 1
    sgemm_rrr<<<dim3(16, 3), 256, 0, stream>>>(g0, Wg1, hf, NSEQ, HH, HH);
    gat_att<<<BB, 256, 0, stream>>>(hf, a1s, a1d, g1);

    // 5) head + masked broadcast
    head_kernel<<<BB, 256, 0, stream>>>(g1, inp, Wa1, ba1, Wa2, ba2, out);
}

// Round 11
// 3058.716 us; speedup vs baseline: 1.5790x; 1.0467x over previous
//
#include <hip/hip_runtime.h>
#include <hip/hip_bf16.h>
#include <cmath>

// Problem constants
#define BB    32
#define SS    256
#define AA    6
#define HH    1024
#define OBSF  520
#define GLOBF 30
#define MASKF 52
#define AGFF  73
#define NSEQ  192   // B*A
#define EMBD  512

#define GRID_GRU 256
#define THR_GRU  192
#define LDS_W_BYTES (48*3*64*16)   // 147456 B
#define HSLOT 196608               // shorts per h buffer (192*1024)
#define NROT  64                   // h-buffer rotation depth
#define INVP  32                   // acquire-fence period (must be < NROT)

typedef short bf16x8 __attribute__((ext_vector_type(8)));
typedef float f32x4  __attribute__((ext_vector_type(4)));

__device__ __forceinline__ float sigmoidf_(float x){ return 1.f/(1.f + expf(-x)); }
__device__ __forceinline__ short f2bf(float x){
    __hip_bfloat16 h = __float2bfloat16(x);
    return *reinterpret_cast<short*>(&h);
}

// ---------------------------------------------------------------------------
__global__ __launch_bounds__(256) void cvt_bf16(
    const float* __restrict__ in, __hip_bfloat16* __restrict__ out, int n)
{
    for (int i = blockIdx.x*256 + threadIdx.x; i < n; i += gridDim.x*256)
        out[i] = __float2bfloat16(in[i]);
}

// ---------------------------------------------------------------------------
// emb[n][s][d] = relu( sum_f vec[n,s,f] * W_emb[ty_n][f][d] + b_emb[ty_n][d] )
// ---------------------------------------------------------------------------
__global__ __launch_bounds__(256) void emb_kernel(
    const float* __restrict__ inp, const float* __restrict__ W_emb,
    const float* __restrict__ b_emb, __hip_bfloat16* __restrict__ emb)
{
    const int n  = blockIdx.x;          // 0..191
    const int s0 = blockIdx.y * 16;
    const int b  = n / AA, a = n % AA;
    const int tid = threadIdx.x;
    const int ty = (int)inp[(size_t)(b*SS)*OBSF + GLOBF + a*AGFF + 1];

    __shared__ float vecs[16][102];
    for (int idx = tid; idx < 16*102; idx += 256) {
        int ss = idx / 102, f = idx % 102;
        int g  = f + 1;
        int col = (g < AGFF) ? (GLOBF + a*AGFF + g) : (g - AGFF);
        vecs[ss][f] = inp[((size_t)(b*SS + s0 + ss))*OBSF + col];
    }
    __syncthreads();

    float acc0[16], acc1[16];
    #pragma unroll
    for (int ss = 0; ss < 16; ++ss) { acc0[ss] = 0.f; acc1[ss] = 0.f; }

    const float* Wb = W_emb + (size_t)ty*102*EMBD;
    for (int f = 0; f < 102; ++f) {
        float w0 = Wb[f*EMBD + tid];
        float w1 = Wb[f*EMBD + tid + 256];
        #pragma unroll
        for (int ss = 0; ss < 16; ++ss) {
            float v = vecs[ss][f];
            acc0[ss] += v * w0;
            acc1[ss] += v * w1;
        }
    }
    float bb0 = b_emb[ty*EMBD + tid], bb1 = b_emb[ty*EMBD + tid + 256];
    for (int ss = 0; ss < 16; ++ss) {
        __hip_bfloat16* o = emb + ((size_t)n*SS + s0 + ss)*EMBD;
        o[tid]       = __float2bfloat16(fmaxf(acc0[ss] + bb0, 0.f));
        o[tid + 256] = __float2bfloat16(fmaxf(acc1[ss] + bb1, 0.f));
    }
}

// ---------------------------------------------------------------------------
// Persistent cooperative GRU, v6 = r10 sync skeleton (unchanged, verified)
// with the h exchange data path rebuilt:
//  - h shadow rotates through NROT=64 distinct buffers (slot = s & 63), so
//    readers can use NORMAL CACHED 16B loads: the XCD L2 absorbs the 64x
//    nt-duplication (24.6 MB/step of 8B bypass transactions -> ~380 KB/XCD
//    of 128B line fills + L2 hits).
//  - staleness on slot reuse (64 steps) is killed by an agent-acquire fence
//    (buffer_inv) every INVP=32 steps: any reuse window provably contains
//    one, and the L2 holds almost no reused data (h/emb are single-use per
//    step) so the inv is nearly free (8 invs/step device-wide vs r4's 512).
//  - writers keep 8B bypass stores (must reach the LLC coherence point).
// grid 256 x 192thr. block = (nt = bx&63, mg = bx>>6); wave w owns m-tile
// mg*3+w. Flag barrier identical to r10.
// ---------------------------------------------------------------------------
__global__ __launch_bounds__(THR_GRU, 1) void gru_persistent(
    const float* __restrict__ state0,
    const short* __restrict__ emb_bf,
    const short* __restrict__ Whh_bf, const short* __restrict__ Wih_bf,
    const float* __restrict__ b_ih, const float* __restrict__ b_hh,
    short* __restrict__ hbase,
    float* __restrict__ hT_out, unsigned* __restrict__ bar)
{
    extern __shared__ short ldsW[];      // [32kt][3g][64lane][8] + [16kt][3g][64lane][8]
    __shared__ short ldsH[3*256];        // per-wave 16x16 bf16 out-tile stage
    const int tid = threadIdx.x, wave = tid >> 6, lane = tid & 63;
    const int nt = blockIdx.x & 63, mg = blockIdx.x >> 6;
    const int i0 = nt*16, mt = mg*3 + wave;
    const int col = lane & 15, rgrp = lane >> 4;
    const int n = i0 + col;
    unsigned* flags = bar + mg*64;       // 64 per-block step flags for this mg

    // ---- stage W into LDS as pre-permuted B-frags (16B cached loads) ----
    for (int idx = tid; idx < 32*3*64; idx += THR_GRU) {
        int l = idx & 63, g = (idx >> 6) % 3, kt = idx / 192;
        const short* src = Whh_bf + ((size_t)(g*HH + i0 + (l & 15)))*HH + kt*32 + (l >> 4)*8;
        *(bf16x8*)(ldsW + (size_t)idx*8) = *(const bf16x8*)src;
    }
    short* ldsW2 = ldsW + 32*3*64*8;
    for (int idx = tid; idx < 16*3*64; idx += THR_GRU) {
        int l = idx & 63, g = (idx >> 6) % 3, kt = idx / 192;
        const short* src = Wih_bf + ((size_t)(g*HH + i0 + (l & 15)))*EMBD + kt*32 + (l >> 4)*8;
        *(bf16x8*)(ldsW2 + (size_t)idx*8) = *(const bf16x8*)src;
    }

    // ---- init h regs + stage bf16 shadow into slot 0 ----
    float hreg[4];
    #pragma unroll
    for (int r_ = 0; r_ < 4; ++r_) {
        hreg[r_] = state0[(size_t)(mt*16 + rgrp*4 + r_)*HH + n];
        ldsH[wave*256 + (rgrp*4 + r_)*16 + col] = f2bf(hreg[r_]);
    }
    __syncthreads();   // W staging + ldsH init complete
    {
        int w2 = tid >> 6, rem = tid & 63, rr = rem >> 2, cg = rem & 3;
        unsigned long long v = *(const unsigned long long*)(ldsH + w2*256 + rr*16 + cg*4);
        __hip_atomic_store((unsigned long long*)(hbase + (size_t)((mg*3 + w2)*16 + rr)*HH + i0 + cg*4),
                           v, __ATOMIC_RELAXED, __HIP_MEMORY_SCOPE_AGENT);
    }
    asm volatile("s_waitcnt vmcnt(0)" ::: "memory");
    __syncthreads();
    if (tid == 0)
        __hip_atomic_store(&flags[nt], 1u, __ATOMIC_RELAXED, __HIP_MEMORY_SCOPE_AGENT);

    const float bir = b_ih[n], biz = b_ih[HH+n], bin_ = b_ih[2*HH+n];
    const float bhr = b_hh[n], bhz = b_hh[HH+n], bhn  = b_hh[2*HH+n];

    const size_t lane_h_off = (size_t)(mt*16 + col)*HH + rgrp*8;
    const size_t lane_e_off = (size_t)(mt*16 + col)*SS*EMBD + rgrp*8;

    // ---- x-part for s = 0 (hidden behind other blocks' init) ----
    f32x4 ax0 = {0.f,0.f,0.f,0.f}, ax1 = ax0, ax3 = ax0;
    {
        const short* Ae = emb_bf + lane_e_off;
        #pragma unroll 8
        for (int kt = 0; kt < 16; ++kt) {
            bf16x8 a  = *(const bf16x8*)(Ae + kt*32);
            bf16x8 b0 = *(const bf16x8*)(ldsW2 + ((kt*3 + 0)*64 + lane)*8);
            bf16x8 b1 = *(const bf16x8*)(ldsW2 + ((kt*3 + 1)*64 + lane)*8);
            bf16x8 b2 = *(const bf16x8*)(ldsW2 + ((kt*3 + 2)*64 + lane)*8);
            ax0 = __builtin_amdgcn_mfma_f32_16x16x32_bf16(a, b0, ax0, 0,0,0);
            ax1 = __builtin_amdgcn_mfma_f32_16x16x32_bf16(a, b1, ax1, 0,0,0);
            ax3 = __builtin_amdgcn_mfma_f32_16x16x32_bf16(a, b2, ax3, 0,0,0);
        }
    }
    if (wave == 0) {
        for (;;) {
            unsigned f = __hip_atomic_load(&flags[lane], __ATOMIC_RELAXED, __HIP_MEMORY_SCOPE_AGENT);
            if (__ballot(f >= 1u) == ~0ull) break;
            __builtin_amdgcn_s_sleep(1);
        }
    }
    __syncthreads();

    for (int s = 0; s < SS; ++s) {
        // Periodic XCD cache invalidate: guarantees no L2/L1 copy older than
        // INVP steps survives; slot reuse distance is NROT > INVP, so cached
        // h reads below can never observe a stale line. (8 invs/step total.)
        if ((s & (INVP-1)) == 0)
            __builtin_amdgcn_fence(__ATOMIC_ACQUIRE, "agent");
        asm volatile("" ::: "memory");   // no load hoisting above barrier/fence

        const short* cur = hbase + (size_t)(s & (NROT-1))*HSLOT;
        short*       nxt = hbase + (size_t)((s+1) & (NROT-1))*HSLOT;

        // ---- h-part: ALL 32 A-frags via NORMAL CACHED 16B loads ----
        const short* Ah = cur + lane_h_off;
        bf16x8 fa[32];
        #pragma unroll
        for (int j = 0; j < 32; ++j) fa[j] = *(const bf16x8*)(Ah + j*32);

        f32x4 a0 = ax0, a1 = ax1, a2 = {0.f,0.f,0.f,0.f};
        #pragma unroll
        for (int kt = 0; kt < 32; ++kt) {
            bf16x8 b0 = *(const bf16x8*)(ldsW + ((kt*3 + 0)*64 + lane)*8);
            bf16x8 b1 = *(const bf16x8*)(ldsW + ((kt*3 + 1)*64 + lane)*8);
            bf16x8 b2 = *(const bf16x8*)(ldsW + ((kt*3 + 2)*64 + lane)*8);
            a0 = __builtin_amdgcn_mfma_f32_16x16x32_bf16(fa[kt], b0, a0, 0,0,0);
            a1 = __builtin_amdgcn_mfma_f32_16x16x32_bf16(fa[kt], b1, a1, 0,0,0);
            a2 = __builtin_amdgcn_mfma_f32_16x16x32_bf16(fa[kt], b2, a2, 0,0,0);
        }

        // ---- epilogue: gates (x-part in ax*), update regs, stage tile ----
        #pragma unroll
        for (int r_ = 0; r_ < 4; ++r_) {
            float r  = sigmoidf_(a0[r_] + bir + bhr);
            float z  = sigmoidf_(a1[r_] + biz + bhz);
            float nn = tanhf(ax3[r_] + bin_ + r*(a2[r_] + bhn));
            float hv = (1.f - z)*nn + z*hreg[r_];
            hreg[r_] = hv;
            ldsH[wave*256 + (rgrp*4 + r_)*16 + col] = f2bf(hv);
        }

        if (s < SS-1) {
            __syncthreads();
            {
                int w2 = tid >> 6, rem = tid & 63, rr = rem >> 2, cg = rem & 3;
                unsigned long long v = *(const unsigned long long*)(ldsH + w2*256 + rr*16 + cg*4);
                __hip_atomic_store((unsigned long long*)(nxt + (size_t)((mg*3 + w2)*16 + rr)*HH + i0 + cg*4),
                                   v, __ATOMIC_RELAXED, __HIP_MEMORY_SCOPE_AGENT);
            }
            asm volatile("s_waitcnt vmcnt(0)" ::: "memory");
            __syncthreads();
            if (tid == 0)
                __hip_atomic_store(&flags[nt], (unsigned)(s + 2), __ATOMIC_RELAXED, __HIP_MEMORY_SCOPE_AGENT);

            // ---- x-part for s+1: hidden inside the barrier wait ----
            ax0 = (f32x4){0.f,0.f,0.f,0.f}; ax1 = ax0; ax3 = ax0;
            const short* Ae = emb_bf + lane_e_off + (size_t)(s+1)*EMBD;
            #pragma unroll 8
            for (int kt = 0; kt < 16; ++kt) {
                bf16x8 a  = *(const bf16x8*)(Ae + kt*32);
                bf16x8 b0 = *(const bf16x8*)(ldsW2 + ((kt*3 + 0)*64 + lane)*8);
                bf16x8 b1 = *(const bf16x8*)(ldsW2 + ((kt*3 + 1)*64 + lane)*8);
                bf16x8 b2 = *(const bf16x8*)(ldsW2 + ((kt*3 + 2)*64 + lane)*8);
                ax0 = __builtin_amdgcn_mfma_f32_16x16x32_bf16(a, b0, ax0, 0,0,0);
                ax1 = __builtin_amdgcn_mfma_f32_16x16x32_bf16(a, b1, ax1, 0,0,0);
                ax3 = __builtin_amdgcn_mfma_f32_16x16x32_bf16(a, b2, ax3, 0,0,0);
            }
            {
                unsigned target = (unsigned)(s + 2);
                if (wave == 0) {
                    for (;;) {
                        unsigned f = __hip_atomic_load(&flags[lane], __ATOMIC_RELAXED, __HIP_MEMORY_SCOPE_AGENT);
                        if (__ballot(f >= target) == ~0ull) break;
                        __builtin_amdgcn_s_sleep(1);
                    }
                }
            }
            __syncthreads();
        }
    }

    #pragma unroll
    for (int r_ = 0; r_ < 4; ++r_)
        hT_out[(size_t)(mt*16 + rgrp*4 + r_)*HH + n] = hreg[r_];
}

// ---------------------------------------------------------------------------
// Fallback per-step GRU kernel (round-2 verified path).
// ---------------------------------------------------------------------------
__global__ __launch_bounds__(256) void gru_step_mfma(
    const float* __restrict__ h_in, const __hip_bfloat16* __restrict__ h_in_bf,
    float* __restrict__ h_out, __hip_bfloat16* __restrict__ h_out_bf,
    const __hip_bfloat16* __restrict__ emb_bf,
    const __hip_bfloat16* __restrict__ Whh_bf, const __hip_bfloat16* __restrict__ Wih_bf,
    const float* __restrict__ b_ih, const float* __restrict__ b_hh, int s)
{
    const int i0   = blockIdx.x * 16;
    const int tid  = threadIdx.x;
    const int wave = tid >> 6, lane = tid & 63;
    const int col  = lane & 15, rgrp = lane >> 4;
    const int n    = i0 + col;
    const int kofs = rgrp * 8;

    f32x4 acc[3][4];
    #pragma unroll
    for (int mi = 0; mi < 3; ++mi)
        #pragma unroll
        for (int g = 0; g < 4; ++g) acc[mi][g] = (f32x4){0.f,0.f,0.f,0.f};

    {
        const short* Ab = (const short*)h_in_bf;
        const short* B0 = (const short*)Whh_bf + ((size_t)(      n))*HH + kofs;
        const short* B1 = (const short*)Whh_bf + ((size_t)(HH  + n))*HH + kofs;
        const short* B2 = (const short*)Whh_bf + ((size_t)(2*HH+ n))*HH + kofs;
        #pragma unroll 2
        for (int kt = 0; kt < 32; ++kt) {
            const int kk = kt * 32;
            bf16x8 b0 = *(const bf16x8*)(B0 + kk);
            bf16x8 b1 = *(const bf16x8*)(B1 + kk);
            bf16x8 b2 = *(const bf16x8*)(B2 + kk);
            #pragma unroll
            for (int mi = 0; mi < 3; ++mi) {
                const int m = (wave*3 + mi)*16 + col;
                bf16x8 a = *(const bf16x8*)(Ab + (size_t)m*HH + kk + kofs);
                acc[mi][0] = __builtin_amdgcn_mfma_f32_16x16x32_bf16(a, b0, acc[mi][0], 0,0,0);
                acc[mi][1] = __builtin_amdgcn_mfma_f32_16x16x32_bf16(a, b1, acc[mi][1], 0,0,0);
                acc[mi][2] = __builtin_amdgcn_mfma_f32_16x16x32_bf16(a, b2, acc[mi][2], 0,0,0);
            }
        }
    }
    {
        const short* Ab = (const short*)emb_bf;
        const short* B0 = (const short*)Wih_bf + ((size_t)(      n))*EMBD + kofs;
        const short* B1 = (const short*)Wih_bf + ((size_t)(HH  + n))*EMBD + kofs;
        const short* B2 = (const short*)Wih_bf + ((size_t)(2*HH+ n))*EMBD + kofs;
        #pragma unroll 2
        for (int kt = 0; kt < 16; ++kt) {
            const int kk = kt * 32;
            bf16x8 b0 = *(const bf16x8*)(B0 + kk);
            bf16x8 b1 = *(const bf16x8*)(B1 + kk);
            bf16x8 b2 = *(const bf16x8*)(B2 + kk);
            #pragma unroll
            for (int mi = 0; mi < 3; ++mi) {
                const int m = (wave*3 + mi)*16 + col;
                bf16x8 a = *(const bf16x8*)(Ab + ((size_t)m*SS + s)*EMBD + kk + kofs);
                acc[mi][0] = __builtin_amdgcn_mfma_f32_16x16x32_bf16(a, b0, acc[mi][0], 0,0,0);
                acc[mi][1] = __builtin_amdgcn_mfma_f32_16x16x32_bf16(a, b1, acc[mi][1], 0,0,0);
                acc[mi][3] = __builtin_amdgcn_mfma_f32_16x16x32_bf16(a, b2, acc[mi][3], 0,0,0);
            }
        }
    }
    const float bir = b_ih[n], biz = b_ih[HH + n], bin_ = b_ih[2*HH + n];
    const float bhr = b_hh[n], bhz = b_hh[HH + n], bhn  = b_hh[2*HH + n];
    #pragma unroll
    for (int mi = 0; mi < 3; ++mi) {
        #pragma unroll
        for (int r_ = 0; r_ < 4; ++r_) {
            const int m = (wave*3 + mi)*16 + rgrp*4 + r_;
            float r  = sigmoidf_(acc[mi][0][r_] + bir + bhr);
            float z  = sigmoidf_(acc[mi][1][r_] + biz + bhz);
            float nn = tanhf(acc[mi][3][r_] + bin_ + r*(acc[mi][2][r_] + bhn));
            const size_t idx = (size_t)m*HH + n;
            float hv = (1.f - z)*nn + z*h_in[idx];
            h_out[idx]    = hv;
            h_out_bf[idx] = __float2bfloat16(hv);
        }
    }
}

// ---------------------------------------------------------------------------
// Generic row-major SGEMM C[M,N] = A[M,K] @ B[K,N]. 64x64 tiles, 4x4/thread.
// ---------------------------------------------------------------------------
__global__ __launch_bounds__(256) void sgemm_rrr(
    const float* __restrict__ A, const float* __restrict__ B,
    float* __restrict__ C, int M, int N, int K)
{
    const int n0 = blockIdx.x * 64;
    const int m0 = blockIdx.y * 64;
    const int tid = threadIdx.x;
    const int tn = tid & 15, tm = tid >> 4;

    __shared__ float As[16][68];
    __shared__ float Bs[16][68];
    float acc[4][4];
    #pragma unroll
    for (int i = 0; i < 4; ++i)
        #pragma unroll
        for (int j = 0; j < 4; ++j) acc[i][j] = 0.f;

    for (int k0 = 0; k0 < K; k0 += 16) {
        {
            int ml = tid >> 2, k4 = (tid & 3) << 2;
            float4 av = *(const float4*)(A + (size_t)(m0 + ml)*K + k0 + k4);
            As[k4 + 0][ml] = av.x; As[k4 + 1][ml] = av.y;
            As[k4 + 2][ml] = av.z; As[k4 + 3][ml] = av.w;
            int kl = tid >> 4, n4 = (tid & 15) << 2;
            *(float4*)&Bs[kl][n4] = *(const float4*)(B + (size_t)(k0 + kl)*N + n0 + n4);
        }
        __syncthreads();
        #pragma unroll
        for (int kk = 0; kk < 16; ++kk) {
            float4 a4 = *(float4*)&As[kk][tm << 2];
            float4 b4 = *(float4*)&Bs[kk][tn << 2];
            acc[0][0] += a4.x*b4.x; acc[0][1] += a4.x*b4.y; acc[0][2] += a4.x*b4.z; acc[0][3] += a4.x*b4.w;
            acc[1][0] += a4.y*b4.x; acc[1][1] += a4.y*b4.y; acc[1][2] += a4.y*b4.z; acc[1][3] += a4.y*b4.w;
            acc[2][0] += a4.z*b4.x; acc[2][1] += a4.z*b4.y; acc[2][2] += a4.z*b4.z; acc[2][3] += a4.z*b4.w;
            acc[3][0] += a4.w*b4.x; acc[3][1] += a4.w*b4.y; acc[3][2] += a4.w*b4.z; acc[3][3] += a4.w*b4.w;
        }
        __syncthreads();
    }
    #pragma unroll
    for (int qm = 0; qm < 4; ++qm) {
        float4 v = make_float4(acc[qm][0], acc[qm][1], acc[qm][2], acc[qm][3]);
        *(float4*)(C + (size_t)(m0 + tm*4 + qm)*N + n0 + tn*4) = v;
    }
}

// ---------------------------------------------------------------------------
// GAT attention. One block per batch b.
// ---------------------------------------------------------------------------
__global__ __launch_bounds__(256) void gat_att(
    const float* __restrict__ hf, const float* __restrict__ a_s,
    const float* __restrict__ a_d, float* __restrict__ gout)
{
    const int b = blockIdx.x;
    const int tid = threadIdx.x;
    __shared__ float hfs[6][1024];
    __shared__ float srcs[24], dsts[24];
    __shared__ float att[4][36];

    for (int idx = tid; idx < 6*1024; idx += 256)
        hfs[idx >> 10][idx & 1023] = hf[(size_t)b*6144 + idx];
    __syncthreads();

    const int w = tid >> 6, lane = tid & 63;
    for (int p = w; p < 24; p += 4) {
        int h = p / 6, nn = p % 6;
        float as_ = 0.f, ad_ = 0.f;
        for (int c = lane; c < 256; c += 64) {
            float v = hfs[nn][h*256 + c];
            as_ += v * a_s[h*256 + c];
            ad_ += v * a_d[h*256 + c];
        }
        #pragma unroll
        for (int off = 32; off; off >>= 1) {
            as_ += __shfl_down(as_, off);
            ad_ += __shfl_down(ad_, off);
        }
        if (lane == 0) { srcs[p] = as_; dsts[p] = ad_; }
    }
    __syncthreads();

    if (tid < 24) {
        int h = tid / 6, i = tid % 6;
        float e[6], mx = -1e30f;
        #pragma unroll
        for (int j = 0; j < 6; ++j) {
            float x = srcs[h*6 + i] + dsts[h*6 + j];
            e[j] = (x >= 0.f) ? x : 0.2f*x;
            mx = fmaxf(mx, e[j]);
        }
        float sum = 0.f;
        #pragma unroll
        for (int j = 0; j < 6; ++j) { e[j] = expf(e[j] - mx); sum += e[j]; }
        float inv = 1.f / sum;
        #pragma unroll
        for (int j = 0; j < 6; ++j) att[h][i*6 + j] = e[j]*inv;
    }
    __syncthreads();

    for (int idx = tid; idx < 6144; idx += 256) {
        int i = idx >> 10, hd = idx & 1023, h = hd >> 8;
        float v = 0.f;
        #pragma unroll
        for (int j = 0; j < 6; ++j) v += att[h][i*6 + j] * hfs[j][hd];
        gout[(size_t)b*6144 + idx] = (v > 0.f) ? v : (expf(v) - 1.f);
    }
}

// ---------------------------------------------------------------------------
// Head. One block per batch b.
// ---------------------------------------------------------------------------
__global__ __launch_bounds__(256) void head_kernel(
    const float* __restrict__ g1, const float* __restrict__ inp,
    const float* __restrict__ Wa1, const float* __restrict__ ba1,
    const float* __restrict__ Wa2, const float* __restrict__ ba2,
    float* __restrict__ out)
{
    const int b = blockIdx.x;
    const int tid = threadIdx.x;
    const int pt = (int)inp[(size_t)b*SS*OBSF + GLOBF + 1];

    __shared__ float f0s[1024];
    __shared__ float h1s[512];
    __shared__ float lgs[52];

    for (int idx = tid; idx < 1024; idx += 256) f0s[idx] = g1[(size_t)b*6144 + idx];
    __syncthreads();
    {
        float acc0 = 0.f, acc1 = 0.f;
        const float* W = Wa1 + (size_t)pt*1024*512;
        for (int f = 0; f < 1024; ++f) {
            float v = f0s[f];
            acc0 += v * W[f*512 + tid];
            acc1 += v * W[f*512 + tid + 256];
        }
        h1s[tid]       = fmaxf(acc0 + ba1[pt*512 + tid], 0.f);
        h1s[tid + 256] = fmaxf(acc1 + ba1[pt*512 + tid + 256], 0.f);
    }
    __syncthreads();
    if (tid < 52) {
        float acc = 0.f;
        const float* W = Wa2 + (size_t)pt*512*52;
        for (int f = 0; f < 512; ++f) acc += h1s[f] * W[f*52 + tid];
        lgs[tid] = acc + ba2[pt*52 + tid];
    }
    __syncthreads();
    for (int idx = tid; idx < SS*MASKF; idx += 256) {
        int s = idx / MASKF, c = idx % MASKF;
        float mv = inp[((size_t)b*SS + s)*OBSF + (OBSF - MASKF) + c];
        out[(size_t)b*SS*MASKF + idx] = (mv != 0.f) ? lgs[c] : 0.f;
    }
}

// ---------------------------------------------------------------------------
extern "C" void kernel_launch(void* const* d_in, const int* in_sizes, int n_in,
                              void* d_out, int out_size, void* d_ws, size_t ws_size,
                              hipStream_t stream)
{
    const float* inp    = (const float*)d_in[0];
    const float* state0 = (const float*)d_in[1];
    const float* W_emb  = (const float*)d_in[2];
    const float* b_emb  = (const float*)d_in[3];
    const float* W_ih   = (const float*)d_in[4];
    const float* W_hh   = (const float*)d_in[5];
    const float* b_ih   = (const float*)d_in[6];
    const float* b_hh   = (const float*)d_in[7];
    const float* Wg0    = (const float*)d_in[8];
    const float* a0s    = (const float*)d_in[9];
    const float* a0d    = (const float*)d_in[10];
    const float* Wg1    = (const float*)d_in[11];
    const float* a1s    = (const float*)d_in[12];
    const float* a1d    = (const float*)d_in[13];
    const float* Wa1    = (const float*)d_in[14];
    const float* ba1    = (const float*)d_in[15];
    const float* Wa2    = (const float*)d_in[16];
    const float* ba2    = (const float*)d_in[17];
    float* out = (float*)d_out;

    // workspace layout (bytes). The h-rotation region (NROT slots) is
    // overlapped with post-GRU scratch: slots 0/1 = fallback bf16 ping-pong,
    // slots 2-5 = fallback fp32 h buffers, slots 6-11 = hf/g0/g1 (post-GRU).
    char* p = (char*)d_ws;
    __hip_bfloat16* emb_bf = (__hip_bfloat16*)p;  p += (size_t)NSEQ*SS*EMBD*2;   // 50.3 MB
    __hip_bfloat16* Whh_bf = (__hip_bfloat16*)p;  p += (size_t)3*HH*HH*2;
    __hip_bfloat16* Wih_bf = (__hip_bfloat16*)p;  p += (size_t)3*HH*EMBD*2;
    unsigned* bar = (unsigned*)p;                 p += 4096;   // 4 mg x 64 flags
    short* hbase = (short*)p;                     p += (size_t)NROT*HSLOT*2;     // 25.2 MB
    if (ws_size < (size_t)(p - (char*)d_ws)) return;

    short* hbf0 = hbase;                    // slot 0 (fallback ping-pong)
    short* hbf1 = hbase + (size_t)HSLOT;    // slot 1
    float* hb0  = (float*)(hbase + (size_t)2*HSLOT);   // slots 2-3 (fallback fp32)
    float* hb1  = (float*)(hbase + (size_t)4*HSLOT);   // slots 4-5
    float* hf   = (float*)(hbase + (size_t)6*HSLOT);   // slots 6-7 (post-GRU)
    float* g0   = (float*)(hbase + (size_t)8*HSLOT);   // slots 8-9
    float* g1   = (float*)(hbase + (size_t)10*HSLOT);  // slots 10-11

    // 0) W -> bf16 (used by both paths)
    cvt_bf16<<<512, 256, 0, stream>>>(W_hh, Whh_bf, 3*HH*HH);
    cvt_bf16<<<512, 256, 0, stream>>>(W_ih, Wih_bf, 3*HH*EMBD);

    // 1) embedding (bf16 out)
    emb_kernel<<<dim3(NSEQ, 16), 256, 0, stream>>>(inp, W_emb, b_emb, emb_bf);

    // 2) GRU: persistent cooperative kernel (fallback: 256-launch loop)
    hipMemsetAsync(bar, 0, 4096, stream);
    float* hT_out = out + (size_t)BB*SS*MASKF;

    static int attr_set = 0;
    if (!attr_set) {
        hipFuncSetAttribute((const void*)gru_persistent,
                            hipFuncAttributeMaxDynamicSharedMemorySize, LDS_W_BYTES);
        attr_set = 1;
    }
    const short* emb_bf_s = (const short*)emb_bf;
    const short* Whh_bf_s = (const short*)Whh_bf;
    const short* Wih_bf_s = (const short*)Wih_bf;
    void* args[] = { (void*)&state0, (void*)&emb_bf_s, (void*)&Whh_bf_s, (void*)&Wih_bf_s,
                     (void*)&b_ih, (void*)&b_hh, (void*)&hbase,
                     (void*)&hT_out, (void*)&bar };
    hipError_t e = hipLaunchCooperativeKernel((const void*)gru_persistent,
                                              dim3(GRID_GRU), dim3(THR_GRU),
                                              args, LDS_W_BYTES, stream);
    const float* hT;
    if (e == hipSuccess) {
        hT = hT_out;
    } else {
        // fallback: round-2 verified path
        cvt_bf16<<<192, 256, 0, stream>>>(state0, (__hip_bfloat16*)hbf0, NSEQ*HH);
        hipMemcpyAsync(hb0, state0, (size_t)NSEQ*HH*4, hipMemcpyDeviceToDevice, stream);
        float* hf32[2] = {hb0, hb1};
        short* hbf[2] = {hbf0, hbf1};
        for (int s = 0; s < SS; ++s) {
            gru_step_mfma<<<64, 256, 0, stream>>>(
                hf32[s & 1], (const __hip_bfloat16*)hbf[s & 1],
                hf32[(s + 1) & 1], (__hip_bfloat16*)hbf[(s + 1) & 1],
                (const __hip_bfloat16*)emb_bf, Whh_bf, Wih_bf, b_ih, b_hh, s);
        }
        hT = hb0;
        hipMemcpyAsync(hT_out, hb0, (size_t)NSEQ*HH*4, hipMemcpyDeviceToDevice, stream);
    }

    // 3) GAT layer 0
    sgemm_rrr<<<dim3(16, 3), 256, 0, stream>>>(hT, Wg0, hf, NSEQ, HH, HH);
    gat_att<<<BB, 256, 0, stream>>>(hf, a0s, a0d, g0);
    // 4) GAT layer 1
    sgemm_rrr<<<dim3(16, 3), 256, 0, stream>>>(g0, Wg1, hf, NSEQ, HH, HH);
    gat_att<<<BB, 256, 0, stream>>>(hf, a1s, a1d, g1);

    // 5) head + masked broadcast
    head_kernel<<<BB, 256, 0, stream>>>(g1, inp, Wa1, ba1, Wa2, ba2, out);
}